// Round 17
// baseline (98.710 us; speedup 1.0000x reference)
//
#include <hip/hip_runtime.h>
#include <math.h>

#define Bsz 64
#define Himg 224
#define HS (Himg*Himg)        // 50176
#define PW 111
#define PP (PW*PW)            // 12321
#define Fn 8
#define FEAT (Fn*PP)          // 98568
#define FEATP 98592           // FEAT padded to multiple of 32 (pad zeroed)
#define KC 32                 // k per tile
#define NT32_TOT 3081         // FEATP/32 k-tiles
#define NCH 192               // chunks; 9x17 + 183x16 = 3081 tiles (balanced)
#define N1 512
#define N2 256
#define N3 1000

typedef short short8 __attribute__((ext_vector_type(8)));
typedef float f32x4 __attribute__((ext_vector_type(4)));

// async global->LDS, 16B per lane; LDS base wave-uniform, global src per-lane
#define GLOAD_LDS16(g, l)                                                     \
  __builtin_amdgcn_global_load_lds(                                           \
      (const __attribute__((address_space(1))) void*)(g),                     \
      (__attribute__((address_space(3))) void*)(l), 16, 0, 0)

// split-float: x = hi + lo (both bf16, truncation split)
__device__ __forceinline__ void cvt_hilo(const float* v, short8& hi, short8& lo) {
#pragma unroll
  for (int j = 0; j < 8; j++) {
    unsigned u = __builtin_bit_cast(unsigned, v[j]);
    hi[j] = (short)(u >> 16);
    float hf = __builtin_bit_cast(float, u & 0xFFFF0000u);
    float r = v[j] - hf;
    lo[j] = (short)(__builtin_bit_cast(unsigned, r) >> 16);
  }
}

// ------- fused: channel-sum + conv3x3 + relu + maxpool -> hi/lo planes -----
// A emitted as two bf16 planes: Ah = truncate(A), Al = bf16(A - Ah).
__global__ void k_convpool(const float* __restrict__ x, const float* __restrict__ filt,
                           short* __restrict__ Ah, short* __restrict__ Al) {
  int i = blockIdx.x * 256 + threadIdx.x;
  if (i < Bsz * (FEATP - FEAT)) {  // zero the 24-elem pad of each batch row
    size_t pidx = (size_t)(i / 24) * FEATP + FEAT + (i % 24);
    Ah[pidx] = 0; Al[pidx] = 0;
  }
  if (i >= Bsz * PP) return;
  int b = i / PP, r = i - b * PP;
  int py = r / PW, px = r - py * PW;
  const float* xb = x + (size_t)b * 3 * HS + (size_t)(2 * py) * Himg + 2 * px;
  float p[4][4];
#pragma unroll
  for (int dy = 0; dy < 4; dy++) {
    const float* row = xb + dy * Himg;
    float2 a0 = *(const float2*)(row);
    float2 a1 = *(const float2*)(row + 2);
    float2 b0 = *(const float2*)(row + HS);
    float2 b1 = *(const float2*)(row + HS + 2);
    float2 c0 = *(const float2*)(row + 2 * HS);
    float2 c1 = *(const float2*)(row + 2 * HS + 2);
    p[dy][0] = a0.x + b0.x + c0.x;
    p[dy][1] = a0.y + b0.y + c0.y;
    p[dy][2] = a1.x + b1.x + c1.x;
    p[dy][3] = a1.y + b1.y + c1.y;
  }
  size_t base = (size_t)b * FEATP + r;
#pragma unroll
  for (int f = 0; f < Fn; f++) {
    float mx = 0.f;
#pragma unroll
    for (int oy = 0; oy < 2; oy++)
#pragma unroll
      for (int ox = 0; ox < 2; ox++) {
        float c = 0.f;
#pragma unroll
        for (int dy = 0; dy < 3; dy++)
#pragma unroll
          for (int dx = 0; dx < 3; dx++)
            c = fmaf(p[oy + dy][ox + dx], filt[f * 9 + dy * 3 + dx], c);
        mx = fmaxf(mx, c);
      }
    unsigned u = __builtin_bit_cast(unsigned, mx);
    float hf = __builtin_bit_cast(float, u & 0xFFFF0000u);
    float rr = mx - hf;
    Ah[base + (size_t)f * PP] = (short)(u >> 16);
    Al[base + (size_t)f * PP] = (short)(__builtin_bit_cast(unsigned, rr) >> 16);
  }
}

// ---------------- GEMM1 split-K via bf16 hi/lo MFMA ------------------------
// C = A(64 x K) @ W(K x 512): Ahi*Whi + Ahi*Wlo + Alo*Whi.
// grid 768 (1D) = 4 n-tiles x 192 balanced chunks = 3 blocks/CU (48 KB LDS).
// XCD co-location: nid = (wgid%8)*96 + wgid/8 (bijective).
// W staged direct-to-LDS (dbuf, XOR-16 column swizzle via pre-swizzled src).
// A staged direct-to-LDS from bf16 hi/lo planes with granule involution
// swizzle: LDS pos p holds source granule p ^ ((row>>1)&3) (pre-swizzled
// per-lane source addr); frag read at granule q ^ ((row>>1)&3) -> 2-way
// banks (free). No pack/unpack VALU in the hot loop. 1 barrier per k-tile.
__global__ void __launch_bounds__(256) k_gemm1(const short* __restrict__ Ah,
                                               const short* __restrict__ Al,
                                               const float* __restrict__ W,
                                               float* __restrict__ partial) {
  __shared__ float Wl[2][KC][128];      // 16 KB x2
  __shared__ short Ashi[2][64 * 32];    // 4 KB x2  [row][4 granules of 8 bf16]
  __shared__ short Aslo[2][64 * 32];    // 4 KB x2
  const int t = threadIdx.x;
  const int wv = t >> 6;
  const int lane = t & 63;
  const int wgid = blockIdx.x;
  const int nid = (wgid & 7) * 96 + (wgid >> 3);   // XCD-coloc remap (768=8*96)
  const int col0b = (nid & 3) * 128;
  const int c = nid >> 2;
  const int tile0 = c * 16 + min(c, 9);
  const int nt = (c < 9) ? 17 : 16;
  const int lrow = lane & 15;
  const int lg8 = (lane >> 4) * 8;
  // W staging (unchanged from r15): wave wv covers k-rows 8wv..8wv+7.
  const int wsr = lane >> 5;           // 0..1
  const int wscx = ((lane & 31) * 4) ^ ((wv & 1) << 4);
  const int wcol = wv * 32 + lrow;
  const int wcolsw = wcol ^ (((lg8 >> 3) & 1) << 4);  // swizzled read col
  // A staging: wave wv covers rows [wv*16, +16); lane -> row l>>2, granule
  // l&3. Source granule pre-swizzled: gs = (l&3) ^ ((row_local>>1)&3).
  const int arl = lane >> 2;           // row local 0..15
  const int ags = (lane & 3) ^ ((arl >> 1) & 3);
  const size_t aoff = (size_t)(wv * 16 + arl) * FEATP + ags * 8;
  // A frag read granule for this thread: q=lane>>4 swizzled per row (in loop)

  f32x4 acc[4][2];
#pragma unroll
  for (int mf = 0; mf < 4; mf++)
#pragma unroll
    for (int nf = 0; nf < 2; nf++)
#pragma unroll
      for (int r = 0; r < 4; r++) acc[mf][nf][r] = 0.f;

#define STAGE_W(buf, kt)                                                      \
  {                                                                           \
    const int kb = (kt) * KC + wv * 8;                                        \
    _Pragma("unroll")                                                         \
    for (int p = 0; p < 4; p++) {                                             \
      int krow = kb + 2 * p + wsr;                                            \
      krow = krow < FEAT ? krow : FEAT - 1;  /* pad rows: A is 0 there */     \
      GLOAD_LDS16(W + (size_t)krow * N1 + col0b + wscx,                       \
                  &Wl[buf][wv * 8 + 2 * p][0]);                               \
    }                                                                         \
  }
#define STAGE_A(buf, kt)                                                      \
  {                                                                           \
    const int kb = (kt) * KC;                                                 \
    GLOAD_LDS16(Ah + aoff + kb, &Ashi[buf][wv * 16 * 32]);                    \
    GLOAD_LDS16(Al + aoff + kb, &Aslo[buf][wv * 16 * 32]);                    \
  }

  // prologue
  STAGE_W(0, tile0)
  STAGE_A(0, tile0)
  __syncthreads();

  for (int s = 0; s < nt; s++) {
    const int buf = s & 1;
    const bool more = (s + 1) < nt;
    if (more) {                         // next-tile loads, in flight all phase
      STAGE_W(buf ^ 1, tile0 + s + 1)
      STAGE_A(buf ^ 1, tile0 + s + 1)
    }
    // ---- B fragments from LDS (swizzled cols, 2-way banks) ----
    float bv0[8], bv1[8];
#pragma unroll
    for (int j = 0; j < 8; j++) {
      bv0[j] = Wl[buf][lg8 + j][wcolsw];
      bv1[j] = Wl[buf][lg8 + j][wcolsw ^ 16];
    }
    short8 bhi[2], blo[2];
    cvt_hilo(bv0, bhi[0], blo[0]);
    cvt_hilo(bv1, bhi[1], blo[1]);
    // ---- A fragments straight from LDS (swizzled granule) + MFMA ----
#pragma unroll
    for (int mf = 0; mf < 4; mf++) {
      const int rr = mf * 16 + lrow;
      const int gq = ((lane >> 4) ^ ((rr >> 1) & 3)) * 8;
      short8 ahi = *(const short8*)&Ashi[buf][rr * 32 + gq];
      short8 alo = *(const short8*)&Aslo[buf][rr * 32 + gq];
#pragma unroll
      for (int nf = 0; nf < 2; nf++) {
        acc[mf][nf] = __builtin_amdgcn_mfma_f32_16x16x32_bf16(ahi, bhi[nf], acc[mf][nf], 0, 0, 0);
        acc[mf][nf] = __builtin_amdgcn_mfma_f32_16x16x32_bf16(ahi, blo[nf], acc[mf][nf], 0, 0, 0);
        acc[mf][nf] = __builtin_amdgcn_mfma_f32_16x16x32_bf16(alo, bhi[nf], acc[mf][nf], 0, 0, 0);
      }
    }
    __syncthreads();
  }

  const int drow = (lane >> 4) * 4;
#pragma unroll
  for (int mf = 0; mf < 4; mf++) {
#pragma unroll
    for (int nf = 0; nf < 2; nf++) {
      float* pp = partial + ((size_t)c * Bsz + mf * 16 + drow) * N1 +
                  col0b + wv * 32 + nf * 16 + lrow;
#pragma unroll
      for (int r = 0; r < 4; r++) pp[(size_t)r * N1] = acc[mf][nf][r];
    }
  }
}

// -------- k_red: h1 = relu(sum_c partial[c] + b1), grid 128x256 ------------
__global__ void k_red(const float* __restrict__ partial, const float* __restrict__ b1,
                      float* __restrict__ h1) {
  int i = blockIdx.x * 256 + threadIdx.x;   // 0..32767
  float sum = 0.f;
#pragma unroll 8
  for (int c = 0; c < NCH; c++) sum += partial[(size_t)c * Bsz * N1 + i];
  h1[i] = fmaxf(sum + b1[i & (N1 - 1)], 0.f);
}

// -------- GEMM2: h2 = relu(h1 @ W2 + b2). grid 256 = (m, n-quarter) --------
__global__ void __launch_bounds__(256) k_gemm2(const float* __restrict__ h1,
                                               const float* __restrict__ W2,
                                               const float* __restrict__ b2,
                                               float* __restrict__ h2) {
  const int m = blockIdx.x >> 2;
  const int nq = blockIdx.x & 3;
  const int t = threadIdx.x;
  __shared__ float a[N1];
  __shared__ float red[4][64];
  a[t] = h1[(size_t)m * N1 + t];
  a[256 + t] = h1[(size_t)m * N1 + 256 + t];
  __syncthreads();
  const int col = nq * 64 + (t & 63);
  const int ks = (t >> 6) * 128;
  float sum = 0.f;
#pragma unroll 8
  for (int k = 0; k < 128; k++)
    sum = fmaf(a[ks + k], W2[(size_t)(ks + k) * N2 + col], sum);
  red[t >> 6][t & 63] = sum;
  __syncthreads();
  if (t < 64) {
    float tot = red[0][t] + red[1][t] + red[2][t] + red[3][t] + b2[nq * 64 + t];
    h2[(size_t)m * N2 + nq * 64 + t] = fmaxf(tot, 0.f);
  }
}

// -------- logits = h2 @ Wo + bo. grid 256 = (m, n-chunk of 250) ------------
__global__ void __launch_bounds__(256) k_logits(const float* __restrict__ h2,
                                                const float* __restrict__ Wo,
                                                const float* __restrict__ bo,
                                                float* __restrict__ logits) {
  const int m = blockIdx.x >> 2;
  const int nc = blockIdx.x & 3;
  const int t = threadIdx.x;
  __shared__ float a[N2];
  a[t] = h2[(size_t)m * N2 + t];
  __syncthreads();
  const int col = nc * 250 + t;
  if (t >= 250) return;
  float sum = bo[col];
#pragma unroll 8
  for (int k = 0; k < N2; k++)
    sum = fmaf(a[k], Wo[(size_t)k * N3 + col], sum);
  logits[(size_t)m * N3 + col] = sum;
}

// -------- softmax over logits rows -> out ----------------------------------
__global__ void __launch_bounds__(256) k_softmax(const float* __restrict__ logits,
                                                 float* __restrict__ out) {
  const int m = blockIdx.x;
  const int t = threadIdx.x;
  __shared__ float red[8];
  float vals[4];
  float vmax = -3.4e38f;
#pragma unroll
  for (int j = 0; j < 4; j++) {
    int n = j * 256 + t;
    vals[j] = (n < N3) ? logits[(size_t)m * N3 + n] : -3.4e38f;
    vmax = fmaxf(vmax, vals[j]);
  }
#pragma unroll
  for (int off = 32; off > 0; off >>= 1) vmax = fmaxf(vmax, __shfl_xor(vmax, off));
  const int wid = t >> 6;
  if ((t & 63) == 0) red[wid] = vmax;
  __syncthreads();
  vmax = fmaxf(fmaxf(red[0], red[1]), fmaxf(red[2], red[3]));
  float ev[4];
  float esum = 0.f;
#pragma unroll
  for (int j = 0; j < 4; j++) {
    int n = j * 256 + t;
    float e = (n < N3) ? __expf(vals[j] - vmax) : 0.f;
    ev[j] = e;
    esum += e;
  }
#pragma unroll
  for (int off = 32; off > 0; off >>= 1) esum += __shfl_xor(esum, off);
  if ((t & 63) == 0) red[4 + wid] = esum;
  __syncthreads();
  esum = red[4] + red[5] + red[6] + red[7];
  float inv = 1.f / esum;
#pragma unroll
  for (int j = 0; j < 4; j++) {
    int n = j * 256 + t;
    if (n < N3) out[(size_t)m * N3 + n] = ev[j] * inv;
  }
}

extern "C" void kernel_launch(void* const* d_in, const int* in_sizes, int n_in,
                              void* d_out, int out_size, void* d_ws, size_t ws_size,
                              hipStream_t stream) {
  const float* x = (const float*)d_in[0];
  const float* filters = (const float*)d_in[1];
  const float* W1 = (const float*)d_in[2];
  const float* b1 = (const float*)d_in[3];
  const float* W2 = (const float*)d_in[4];
  const float* b2 = (const float*)d_in[5];
  const float* Wo = (const float*)d_in[6];
  const float* bo = (const float*)d_in[7];
  float* out = (float*)d_out;

  short* Ah = (short*)d_ws;                          // 64*98592 bf16
  short* Al = Ah + (size_t)Bsz * FEATP;              // 64*98592 bf16
  float* partial = (float*)(Al + (size_t)Bsz * FEATP);  // 192*64*512
  float* h1 = partial + (size_t)NCH * Bsz * N1;      // 64*512
  float* h2 = h1 + (size_t)Bsz * N1;                 // 64*256
  float* logits = h2 + (size_t)Bsz * N2;             // 64*1000

  k_convpool<<<(Bsz * PP + 255) / 256, 256, 0, stream>>>(x, filters, Ah, Al);
  k_gemm1<<<4 * NCH, 256, 0, stream>>>(Ah, Al, W1, partial);
  k_red<<<Bsz * N1 / 256, 256, 0, stream>>>(partial, b1, h1);
  k_gemm2<<<Bsz * 4, 256, 0, stream>>>(h1, W2, b2, h2);
  k_logits<<<Bsz * 4, 256, 0, stream>>>(h2, Wo, bo, logits);
  k_softmax<<<Bsz, 256, 0, stream>>>(logits, out);
}

// Round 18
// 94.165 us; speedup vs baseline: 1.0483x; 1.0483x over previous
//
#include <hip/hip_runtime.h>
#include <math.h>

#define Bsz 64
#define Himg 224
#define HS (Himg*Himg)        // 50176
#define PW 111
#define PP (PW*PW)            // 12321
#define Fn 8
#define FEAT (Fn*PP)          // 98568
#define FEATP 98592           // FEAT padded to multiple of 32 (pad zeroed)
#define KC 32                 // k per tile
#define NT32_TOT 3081         // FEATP/32 k-tiles
#define NCH 192               // chunks; 9x17 + 183x16 = 3081 tiles (balanced)
#define N1 512
#define N2 256
#define N3 1000

typedef short short8 __attribute__((ext_vector_type(8)));
typedef float f32x4 __attribute__((ext_vector_type(4)));

// async global->LDS, 16B per lane; LDS base wave-uniform, global src per-lane
#define GLOAD_LDS16(g, l)                                                     \
  __builtin_amdgcn_global_load_lds(                                           \
      (const __attribute__((address_space(1))) void*)(g),                     \
      (__attribute__((address_space(3))) void*)(l), 16, 0, 0)

// split-float: x = hi + lo (both bf16, truncation split)
__device__ __forceinline__ void cvt_hilo(const float* v, short8& hi, short8& lo) {
#pragma unroll
  for (int j = 0; j < 8; j++) {
    unsigned u = __builtin_bit_cast(unsigned, v[j]);
    hi[j] = (short)(u >> 16);
    float hf = __builtin_bit_cast(float, u & 0xFFFF0000u);
    float r = v[j] - hf;
    lo[j] = (short)(__builtin_bit_cast(unsigned, r) >> 16);
  }
}

// pack one float into (bf16hi<<16)|bf16lo
__device__ __forceinline__ unsigned packhl(float f) {
  unsigned u = __builtin_bit_cast(unsigned, f);
  unsigned hi = u >> 16;
  float hf = __builtin_bit_cast(float, u & 0xFFFF0000u);
  float r = f - hf;
  unsigned lo = __builtin_bit_cast(unsigned, r) >> 16;
  return (hi << 16) | (lo & 0xFFFFu);
}

__device__ __forceinline__ uint4 pack4(float4 f) {
  uint4 o;
  o.x = packhl(f.x); o.y = packhl(f.y); o.z = packhl(f.z); o.w = packhl(f.w);
  return o;
}

// ------- fused: channel-sum + conv3x3 (8 filt) + relu + maxpool -> flat ----
__global__ void k_convpool(const float* __restrict__ x, const float* __restrict__ filt,
                           float* __restrict__ flat) {
  int i = blockIdx.x * 256 + threadIdx.x;
  if (i < Bsz * (FEATP - FEAT))  // zero the 24-float pad of each batch row
    flat[(size_t)(i / 24) * FEATP + FEAT + (i % 24)] = 0.f;
  if (i >= Bsz * PP) return;
  int b = i / PP, r = i - b * PP;
  int py = r / PW, px = r - py * PW;
  const float* xb = x + (size_t)b * 3 * HS + (size_t)(2 * py) * Himg + 2 * px;
  float p[4][4];
#pragma unroll
  for (int dy = 0; dy < 4; dy++) {
    const float* row = xb + dy * Himg;
    float2 a0 = *(const float2*)(row);
    float2 a1 = *(const float2*)(row + 2);
    float2 b0 = *(const float2*)(row + HS);
    float2 b1 = *(const float2*)(row + HS + 2);
    float2 c0 = *(const float2*)(row + 2 * HS);
    float2 c1 = *(const float2*)(row + 2 * HS + 2);
    p[dy][0] = a0.x + b0.x + c0.x;
    p[dy][1] = a0.y + b0.y + c0.y;
    p[dy][2] = a1.x + b1.x + c1.x;
    p[dy][3] = a1.y + b1.y + c1.y;
  }
  float* outb = flat + (size_t)b * FEATP + r;
#pragma unroll
  for (int f = 0; f < Fn; f++) {
    float mx = 0.f;
#pragma unroll
    for (int oy = 0; oy < 2; oy++)
#pragma unroll
      for (int ox = 0; ox < 2; ox++) {
        float c = 0.f;
#pragma unroll
        for (int dy = 0; dy < 3; dy++)
#pragma unroll
          for (int dx = 0; dx < 3; dx++)
            c = fmaf(p[oy + dy][ox + dx], filt[f * 9 + dy * 3 + dx], c);
        mx = fmaxf(mx, c);
      }
    outb[(size_t)f * PP] = mx;
  }
}

// ---------------- GEMM1 split-K via bf16 hi/lo MFMA ------------------------
// C = A(64 x K) @ W(K x 512): Ahi*Whi + Ahi*Wlo + Alo*Whi.
// grid 768 (1D) = 4 n-tiles x 192 balanced chunks = 3 blocks/CU (48 KB LDS).
// XCD co-location: nid = (wgid%8)*96 + wgid/8 (bijective) puts the 4 n-tile
// blocks of each chunk on ONE XCD -> shared A-slice hits L2.
// W staged direct-to-LDS (global_load_lds, dbuf) with XOR-16 column swizzle
// via pre-swizzled source; A reg-staged as packed (hi<<16|lo) u32,
// XOR-swizzled granules. 1 barrier per k-tile.
// Epilogue: fire-and-forget global_atomic_add_f32 into h1acc (L3 far-atomic,
// cross-XCD safe) -- deletes the partial round-trip + red1a kernel.
__global__ void __launch_bounds__(256) k_gemm1(const float* __restrict__ A,
                                               const float* __restrict__ W,
                                               float* __restrict__ h1acc) {
  __shared__ float Wl[2][KC][128];      // 16 KB x2
  __shared__ unsigned As[2][64 * 32];   // 8 KB x2, [row][32 u32 swizzled]
  const int t = threadIdx.x;
  const int wv = t >> 6;
  const int lane = t & 63;
  const int wgid = blockIdx.x;
  const int nid = (wgid & 7) * 96 + (wgid >> 3);   // XCD-coloc remap (768=8*96)
  const int col0b = (nid & 3) * 128;
  const int c = nid >> 2;
  const int tile0 = c * 16 + min(c, 9);
  const int nt = (c < 9) ? 17 : 16;
  const int lrow = lane & 15;
  const int lg8 = (lane >> 4) * 8;
  const int gr = lg8 >> 2;             // base granule for A-frag reads
  // A staging: lane covers rows sr, sr+8, granule sq (4 floats)
  const int sr = wv * 16 + (lane >> 3);
  const int sq = lane & 7;
  const int sgs = ((sq ^ (sr & 7)) << 2);
  const float* Ast = A + (size_t)sr * FEATP + sq * 4;
  // W staging: wave wv covers k-rows 8wv..8wv+7, 4 gloads of 2 rows each.
  // source col pre-swizzled with the wave's row-block key ((wv&1)<<4) so the
  // linear LDS dest holds Wl[r][c'] = W[r][c' ^ (((r>>3)&1)<<4)].
  const int wsr = lane >> 5;           // 0..1
  const int wscx = ((lane & 31) * 4) ^ ((wv & 1) << 4);
  const int wcol = wv * 32 + lrow;     // this wave's B col base (nf=0)
  const int wcolsw = wcol ^ (((lg8 >> 3) & 1) << 4);  // swizzled read col

  f32x4 acc[4][2];
#pragma unroll
  for (int mf = 0; mf < 4; mf++)
#pragma unroll
    for (int nf = 0; nf < 2; nf++)
#pragma unroll
      for (int r = 0; r < 4; r++) acc[mf][nf][r] = 0.f;

  float4 fa0, fa1;

#define STAGE_W(buf, kt)                                                      \
  {                                                                           \
    const int kb = (kt) * KC + wv * 8;                                        \
    _Pragma("unroll")                                                         \
    for (int p = 0; p < 4; p++) {                                             \
      int krow = kb + 2 * p + wsr;                                            \
      krow = krow < FEAT ? krow : FEAT - 1;  /* pad rows: A is 0 there */     \
      GLOAD_LDS16(W + (size_t)krow * N1 + col0b + wscx,                       \
                  &Wl[buf][wv * 8 + 2 * p][0]);                               \
    }                                                                         \
  }

  auto loadA = [&](int kb) {
    fa0 = *(const float4*)(Ast + kb);
    fa1 = *(const float4*)(Ast + (size_t)8 * FEATP + kb);
  };
  auto writeA = [&](int buf) {
    *(uint4*)&As[buf][sr * 32 + sgs] = pack4(fa0);
    *(uint4*)&As[buf][(sr + 8) * 32 + sgs] = pack4(fa1);
  };

  // prologue
  STAGE_W(0, tile0)
  loadA(tile0 * KC);
  writeA(0);
  __syncthreads();

  for (int s = 0; s < nt; s++) {
    const int buf = s & 1;
    const bool more = (s + 1) < nt;
    if (more) {                         // next-tile loads, in flight all phase
      STAGE_W(buf ^ 1, tile0 + s + 1)
      loadA((tile0 + s + 1) * KC);
    }
    // ---- B fragments from LDS (swizzled cols, 2-way banks) ----
    float bv0[8], bv1[8];
#pragma unroll
    for (int j = 0; j < 8; j++) {
      bv0[j] = Wl[buf][lg8 + j][wcolsw];
      bv1[j] = Wl[buf][lg8 + j][wcolsw ^ 16];
    }
    short8 bhi[2], blo[2];
    cvt_hilo(bv0, bhi[0], blo[0]);
    cvt_hilo(bv1, bhi[1], blo[1]);
    // ---- A fragments + MFMA ----
#pragma unroll
    for (int mf = 0; mf < 4; mf++) {
      const int r = mf * 16 + lrow;
      const int key = (r & 7);
      unsigned au[8];
      *(uint4*)(au + 0) = *(const uint4*)&As[buf][r * 32 + ((gr ^ key) << 2)];
      *(uint4*)(au + 4) = *(const uint4*)&As[buf][r * 32 + (((gr + 1) ^ key) << 2)];
      short8 ahi, alo;
#pragma unroll
      for (int j = 0; j < 8; j++) {
        ahi[j] = (short)(au[j] >> 16);
        alo[j] = (short)(au[j] & 0xFFFFu);
      }
#pragma unroll
      for (int nf = 0; nf < 2; nf++) {
        acc[mf][nf] = __builtin_amdgcn_mfma_f32_16x16x32_bf16(ahi, bhi[nf], acc[mf][nf], 0, 0, 0);
        acc[mf][nf] = __builtin_amdgcn_mfma_f32_16x16x32_bf16(ahi, blo[nf], acc[mf][nf], 0, 0, 0);
        acc[mf][nf] = __builtin_amdgcn_mfma_f32_16x16x32_bf16(alo, bhi[nf], acc[mf][nf], 0, 0, 0);
      }
    }
    if (more) writeA(buf ^ 1);
    __syncthreads();
  }

  const int drow = (lane >> 4) * 4;
#pragma unroll
  for (int mf = 0; mf < 4; mf++) {
#pragma unroll
    for (int nf = 0; nf < 2; nf++) {
      float* pp = h1acc + (size_t)(mf * 16 + drow) * N1 +
                  col0b + wv * 32 + nf * 16 + lrow;
#pragma unroll
      for (int r = 0; r < 4; r++)
        atomicAdd(pp + (size_t)r * N1, acc[mf][nf][r]);   // no-return far atomic
    }
  }
}

// -------- GEMM2 (+bias/relu on h1acc): h2 = relu(relu(h1acc+b1) @ W2 + b2) -
__global__ void __launch_bounds__(256) k_gemm2(const float* __restrict__ h1acc,
                                               const float* __restrict__ b1,
                                               const float* __restrict__ W2,
                                               const float* __restrict__ b2,
                                               float* __restrict__ h2) {
  const int m = blockIdx.x >> 2;
  const int nq = blockIdx.x & 3;
  const int t = threadIdx.x;
  __shared__ float a[N1];
  __shared__ float red[4][64];
#pragma unroll
  for (int e = 0; e < 2; e++) {
    int idx = e * 256 + t;
    a[idx] = fmaxf(h1acc[(size_t)m * N1 + idx] + b1[idx], 0.f);
  }
  __syncthreads();
  const int col = nq * 64 + (t & 63);
  const int ks = (t >> 6) * 128;
  float sum = 0.f;
#pragma unroll 8
  for (int k = 0; k < 128; k++)
    sum = fmaf(a[ks + k], W2[(size_t)(ks + k) * N2 + col], sum);
  red[t >> 6][t & 63] = sum;
  __syncthreads();
  if (t < 64) {
    float tot = red[0][t] + red[1][t] + red[2][t] + red[3][t] + b2[nq * 64 + t];
    h2[(size_t)m * N2 + nq * 64 + t] = fmaxf(tot, 0.f);
  }
}

// -------- logits = h2 @ Wo + bo. grid 256 = (m, n-chunk of 250) ------------
__global__ void __launch_bounds__(256) k_logits(const float* __restrict__ h2,
                                                const float* __restrict__ Wo,
                                                const float* __restrict__ bo,
                                                float* __restrict__ logits) {
  const int m = blockIdx.x >> 2;
  const int nc = blockIdx.x & 3;
  const int t = threadIdx.x;
  __shared__ float a[N2];
  a[t] = h2[(size_t)m * N2 + t];
  __syncthreads();
  const int col = nc * 250 + t;
  if (t >= 250) return;
  float sum = bo[col];
#pragma unroll 8
  for (int k = 0; k < N2; k++)
    sum = fmaf(a[k], Wo[(size_t)k * N3 + col], sum);
  logits[(size_t)m * N3 + col] = sum;
}

// -------- softmax over logits rows -> out ----------------------------------
__global__ void __launch_bounds__(256) k_softmax(const float* __restrict__ logits,
                                                 float* __restrict__ out) {
  const int m = blockIdx.x;
  const int t = threadIdx.x;
  __shared__ float red[8];
  float vals[4];
  float vmax = -3.4e38f;
#pragma unroll
  for (int j = 0; j < 4; j++) {
    int n = j * 256 + t;
    vals[j] = (n < N3) ? logits[(size_t)m * N3 + n] : -3.4e38f;
    vmax = fmaxf(vmax, vals[j]);
  }
#pragma unroll
  for (int off = 32; off > 0; off >>= 1) vmax = fmaxf(vmax, __shfl_xor(vmax, off));
  const int wid = t >> 6;
  if ((t & 63) == 0) red[wid] = vmax;
  __syncthreads();
  vmax = fmaxf(fmaxf(red[0], red[1]), fmaxf(red[2], red[3]));
  float ev[4];
  float esum = 0.f;
#pragma unroll
  for (int j = 0; j < 4; j++) {
    int n = j * 256 + t;
    float e = (n < N3) ? __expf(vals[j] - vmax) : 0.f;
    ev[j] = e;
    esum += e;
  }
#pragma unroll
  for (int off = 32; off > 0; off >>= 1) esum += __shfl_xor(esum, off);
  if ((t & 63) == 0) red[4 + wid] = esum;
  __syncthreads();
  esum = red[4] + red[5] + red[6] + red[7];
  float inv = 1.f / esum;
#pragma unroll
  for (int j = 0; j < 4; j++) {
    int n = j * 256 + t;
    if (n < N3) out[(size_t)m * N3 + n] = ev[j] * inv;
  }
}

extern "C" void kernel_launch(void* const* d_in, const int* in_sizes, int n_in,
                              void* d_out, int out_size, void* d_ws, size_t ws_size,
                              hipStream_t stream) {
  const float* x = (const float*)d_in[0];
  const float* filters = (const float*)d_in[1];
  const float* W1 = (const float*)d_in[2];
  const float* b1 = (const float*)d_in[3];
  const float* W2 = (const float*)d_in[4];
  const float* b2 = (const float*)d_in[5];
  const float* Wo = (const float*)d_in[6];
  const float* bo = (const float*)d_in[7];
  float* out = (float*)d_out;

  float* ws = (float*)d_ws;
  float* flat = ws;                                  // 64*98592 (padded)
  float* h1acc = flat + (size_t)Bsz * FEATP;         // 64*512 atomic accum
  float* h2 = h1acc + (size_t)Bsz * N1;              // 64*256
  float* logits = h2 + (size_t)Bsz * N2;             // 64*1000

  k_convpool<<<(Bsz * PP + 255) / 256, 256, 0, stream>>>(x, filters, flat);
  hipMemsetAsync(h1acc, 0, (size_t)Bsz * N1 * sizeof(float), stream);
  k_gemm1<<<4 * NCH, 256, 0, stream>>>(flat, W1, h1acc);
  k_gemm2<<<Bsz * 4, 256, 0, stream>>>(h1acc, b1, W2, b2, h2);
  k_logits<<<Bsz * 4, 256, 0, stream>>>(h2, Wo, bo, logits);
  k_softmax<<<Bsz, 256, 0, stream>>>(logits, out);
}

// Round 19
// 89.649 us; speedup vs baseline: 1.1011x; 1.0504x over previous
//
#include <hip/hip_runtime.h>
#include <math.h>

#define Bsz 64
#define Himg 224
#define HS (Himg*Himg)        // 50176
#define PW 111
#define PP (PW*PW)            // 12321
#define Fn 8
#define FEAT (Fn*PP)          // 98568
#define FEATP 98592           // FEAT padded to multiple of 32 (pad zeroed)
#define KC 32                 // k per tile
#define NT32_TOT 3081         // FEATP/32 k-tiles
#define NCH 192               // chunks; 9x17 + 183x16 = 3081 tiles (balanced)
#define N1 512
#define N2 256
#define N3 1000
#define RG 8                  // red1 k-groups (24 chunks each)

typedef short short8 __attribute__((ext_vector_type(8)));
typedef float f32x4 __attribute__((ext_vector_type(4)));

// async global->LDS, 16B per lane; LDS base wave-uniform, global src per-lane
#define GLOAD_LDS16(g, l)                                                     \
  __builtin_amdgcn_global_load_lds(                                           \
      (const __attribute__((address_space(1))) void*)(g),                     \
      (__attribute__((address_space(3))) void*)(l), 16, 0, 0)

// split-float: x = hi + lo (both bf16, truncation split)
__device__ __forceinline__ void cvt_hilo(const float* v, short8& hi, short8& lo) {
#pragma unroll
  for (int j = 0; j < 8; j++) {
    unsigned u = __builtin_bit_cast(unsigned, v[j]);
    hi[j] = (short)(u >> 16);
    float hf = __builtin_bit_cast(float, u & 0xFFFF0000u);
    float r = v[j] - hf;
    lo[j] = (short)(__builtin_bit_cast(unsigned, r) >> 16);
  }
}

// pack one float into (bf16hi<<16)|bf16lo
__device__ __forceinline__ unsigned packhl(float f) {
  unsigned u = __builtin_bit_cast(unsigned, f);
  unsigned hi = u >> 16;
  float hf = __builtin_bit_cast(float, u & 0xFFFF0000u);
  float r = f - hf;
  unsigned lo = __builtin_bit_cast(unsigned, r) >> 16;
  return (hi << 16) | (lo & 0xFFFFu);
}

__device__ __forceinline__ uint4 pack4(float4 f) {
  uint4 o;
  o.x = packhl(f.x); o.y = packhl(f.y); o.z = packhl(f.z); o.w = packhl(f.w);
  return o;
}

// ------- fused: channel-sum + conv3x3 (8 filt) + relu + maxpool -> flat ----
__global__ void k_convpool(const float* __restrict__ x, const float* __restrict__ filt,
                           float* __restrict__ flat) {
  int i = blockIdx.x * 256 + threadIdx.x;
  if (i < Bsz * (FEATP - FEAT))  // zero the 24-float pad of each batch row
    flat[(size_t)(i / 24) * FEATP + FEAT + (i % 24)] = 0.f;
  if (i >= Bsz * PP) return;
  int b = i / PP, r = i - b * PP;
  int py = r / PW, px = r - py * PW;
  const float* xb = x + (size_t)b * 3 * HS + (size_t)(2 * py) * Himg + 2 * px;
  float p[4][4];
#pragma unroll
  for (int dy = 0; dy < 4; dy++) {
    const float* row = xb + dy * Himg;
    float2 a0 = *(const float2*)(row);
    float2 a1 = *(const float2*)(row + 2);
    float2 b0 = *(const float2*)(row + HS);
    float2 b1 = *(const float2*)(row + HS + 2);
    float2 c0 = *(const float2*)(row + 2 * HS);
    float2 c1 = *(const float2*)(row + 2 * HS + 2);
    p[dy][0] = a0.x + b0.x + c0.x;
    p[dy][1] = a0.y + b0.y + c0.y;
    p[dy][2] = a1.x + b1.x + c1.x;
    p[dy][3] = a1.y + b1.y + c1.y;
  }
  float* outb = flat + (size_t)b * FEATP + r;
#pragma unroll
  for (int f = 0; f < Fn; f++) {
    float mx = 0.f;
#pragma unroll
    for (int oy = 0; oy < 2; oy++)
#pragma unroll
      for (int ox = 0; ox < 2; ox++) {
        float c = 0.f;
#pragma unroll
        for (int dy = 0; dy < 3; dy++)
#pragma unroll
          for (int dx = 0; dx < 3; dx++)
            c = fmaf(p[oy + dy][ox + dx], filt[f * 9 + dy * 3 + dx], c);
        mx = fmaxf(mx, c);
      }
    outb[(size_t)f * PP] = mx;
  }
}

// ---------------- GEMM1 split-K via bf16 hi/lo MFMA ------------------------
// C = A(64 x K) @ W(K x 512): Ahi*Whi + Ahi*Wlo + Alo*Whi.
// grid 768 (1D) = 4 n-tiles x 192 balanced chunks = 3 blocks/CU (48 KB LDS).
// XCD co-location: nid = (wgid%8)*96 + wgid/8 (bijective) puts the 4 n-tile
// blocks of each chunk on ONE XCD -> shared 128KB A-slice hits L2.
// W staged direct-to-LDS (global_load_lds, dbuf) with XOR-16 column swizzle
// via pre-swizzled source; A reg-staged as packed (hi<<16|lo) u32,
// XOR-swizzled granules. 1 barrier per k-tile.
__global__ void __launch_bounds__(256) k_gemm1(const float* __restrict__ A,
                                               const float* __restrict__ W,
                                               float* __restrict__ partial) {
  __shared__ float Wl[2][KC][128];      // 16 KB x2
  __shared__ unsigned As[2][64 * 32];   // 8 KB x2, [row][32 u32 swizzled]
  const int t = threadIdx.x;
  const int wv = t >> 6;
  const int lane = t & 63;
  const int wgid = blockIdx.x;
  const int nid = (wgid & 7) * 96 + (wgid >> 3);   // XCD-coloc remap (768=8*96)
  const int col0b = (nid & 3) * 128;
  const int c = nid >> 2;
  const int tile0 = c * 16 + min(c, 9);
  const int nt = (c < 9) ? 17 : 16;
  const int lrow = lane & 15;
  const int lg8 = (lane >> 4) * 8;
  const int gr = lg8 >> 2;             // base granule for A-frag reads
  // A staging: lane covers rows sr, sr+8, granule sq (4 floats)
  const int sr = wv * 16 + (lane >> 3);
  const int sq = lane & 7;
  const int sgs = ((sq ^ (sr & 7)) << 2);
  const float* Ast = A + (size_t)sr * FEATP + sq * 4;
  // W staging: wave wv covers k-rows 8wv..8wv+7, 4 gloads of 2 rows each.
  // source col pre-swizzled with the wave's row-block key ((wv&1)<<4) so the
  // linear LDS dest holds Wl[r][c'] = W[r][c' ^ (((r>>3)&1)<<4)].
  const int wsr = lane >> 5;           // 0..1
  const int wscx = ((lane & 31) * 4) ^ ((wv & 1) << 4);
  const int wcol = wv * 32 + lrow;     // this wave's B col base (nf=0)
  const int wcolsw = wcol ^ (((lg8 >> 3) & 1) << 4);  // swizzled read col

  f32x4 acc[4][2];
#pragma unroll
  for (int mf = 0; mf < 4; mf++)
#pragma unroll
    for (int nf = 0; nf < 2; nf++)
#pragma unroll
      for (int r = 0; r < 4; r++) acc[mf][nf][r] = 0.f;

  float4 fa0, fa1;

#define STAGE_W(buf, kt)                                                      \
  {                                                                           \
    const int kb = (kt) * KC + wv * 8;                                        \
    _Pragma("unroll")                                                         \
    for (int p = 0; p < 4; p++) {                                             \
      int krow = kb + 2 * p + wsr;                                            \
      krow = krow < FEAT ? krow : FEAT - 1;  /* pad rows: A is 0 there */     \
      GLOAD_LDS16(W + (size_t)krow * N1 + col0b + wscx,                       \
                  &Wl[buf][wv * 8 + 2 * p][0]);                               \
    }                                                                         \
  }

  auto loadA = [&](int kb) {
    fa0 = *(const float4*)(Ast + kb);
    fa1 = *(const float4*)(Ast + (size_t)8 * FEATP + kb);
  };
  auto writeA = [&](int buf) {
    *(uint4*)&As[buf][sr * 32 + sgs] = pack4(fa0);
    *(uint4*)&As[buf][(sr + 8) * 32 + sgs] = pack4(fa1);
  };

  // prologue
  STAGE_W(0, tile0)
  loadA(tile0 * KC);
  writeA(0);
  __syncthreads();

  for (int s = 0; s < nt; s++) {
    const int buf = s & 1;
    const bool more = (s + 1) < nt;
    if (more) {                         // next-tile loads, in flight all phase
      STAGE_W(buf ^ 1, tile0 + s + 1)
      loadA((tile0 + s + 1) * KC);
    }
    // ---- B fragments from LDS (swizzled cols, 2-way banks) ----
    float bv0[8], bv1[8];
#pragma unroll
    for (int j = 0; j < 8; j++) {
      bv0[j] = Wl[buf][lg8 + j][wcolsw];
      bv1[j] = Wl[buf][lg8 + j][wcolsw ^ 16];
    }
    short8 bhi[2], blo[2];
    cvt_hilo(bv0, bhi[0], blo[0]);
    cvt_hilo(bv1, bhi[1], blo[1]);
    // ---- A fragments + MFMA ----
#pragma unroll
    for (int mf = 0; mf < 4; mf++) {
      const int r = mf * 16 + lrow;
      const int key = (r & 7);
      unsigned au[8];
      *(uint4*)(au + 0) = *(const uint4*)&As[buf][r * 32 + ((gr ^ key) << 2)];
      *(uint4*)(au + 4) = *(const uint4*)&As[buf][r * 32 + (((gr + 1) ^ key) << 2)];
      short8 ahi, alo;
#pragma unroll
      for (int j = 0; j < 8; j++) {
        ahi[j] = (short)(au[j] >> 16);
        alo[j] = (short)(au[j] & 0xFFFFu);
      }
#pragma unroll
      for (int nf = 0; nf < 2; nf++) {
        acc[mf][nf] = __builtin_amdgcn_mfma_f32_16x16x32_bf16(ahi, bhi[nf], acc[mf][nf], 0, 0, 0);
        acc[mf][nf] = __builtin_amdgcn_mfma_f32_16x16x32_bf16(ahi, blo[nf], acc[mf][nf], 0, 0, 0);
        acc[mf][nf] = __builtin_amdgcn_mfma_f32_16x16x32_bf16(alo, bhi[nf], acc[mf][nf], 0, 0, 0);
      }
    }
    if (more) writeA(buf ^ 1);
    __syncthreads();
  }

  const int drow = (lane >> 4) * 4;
#pragma unroll
  for (int mf = 0; mf < 4; mf++) {
#pragma unroll
    for (int nf = 0; nf < 2; nf++) {
      float* pp = partial + ((size_t)c * Bsz + mf * 16 + drow) * N1 +
                  col0b + wv * 32 + nf * 16 + lrow;
#pragma unroll
      for (int r = 0; r < 4; r++) pp[(size_t)r * N1] = acc[mf][nf][r];
    }
  }
}

// -------- red1a: partial[192][64][512] -> partial2[8][64*512] (float4) -----
__global__ void k_red1a(const float4* __restrict__ partial, float4* __restrict__ partial2) {
  int i = blockIdx.x * 256 + threadIdx.x;   // float4 elem 0..8191
  int g = blockIdx.y;
  int c0 = g * 24;
  const int Q = Bsz * N1 / 4;
  float4 s = make_float4(0.f, 0.f, 0.f, 0.f);
#pragma unroll 4
  for (int c = c0; c < c0 + 24; c++) {
    float4 v = partial[(size_t)c * Q + i];
    s.x += v.x; s.y += v.y; s.z += v.z; s.w += v.w;
  }
  partial2[(size_t)g * Q + i] = s;
}

// -------- GEMM2 (+fused red1b): h2 = relu(relu(red+b1) @ W2 + b2) ----------
__global__ void __launch_bounds__(256) k_gemm2(const float* __restrict__ partial2,
                                               const float* __restrict__ b1,
                                               const float* __restrict__ W2,
                                               const float* __restrict__ b2,
                                               float* __restrict__ h2) {
  const int m = blockIdx.x >> 2;
  const int nq = blockIdx.x & 3;
  const int t = threadIdx.x;
  __shared__ float a[N1];
  __shared__ float red[4][64];
  // build h1 row m in LDS (8-group reduce + bias + relu)
#pragma unroll
  for (int e = 0; e < 2; e++) {
    int idx = e * 256 + t;
    float sum = 0.f;
#pragma unroll
    for (int g = 0; g < RG; g++)
      sum += partial2[(size_t)g * Bsz * N1 + (size_t)m * N1 + idx];
    a[idx] = fmaxf(sum + b1[idx], 0.f);
  }
  __syncthreads();
  const int col = nq * 64 + (t & 63);
  const int ks = (t >> 6) * 128;
  float sum = 0.f;
#pragma unroll 8
  for (int k = 0; k < 128; k++)
    sum = fmaf(a[ks + k], W2[(size_t)(ks + k) * N2 + col], sum);
  red[t >> 6][t & 63] = sum;
  __syncthreads();
  if (t < 64) {
    float tot = red[0][t] + red[1][t] + red[2][t] + red[3][t] + b2[nq * 64 + t];
    h2[(size_t)m * N2 + nq * 64 + t] = fmaxf(tot, 0.f);
  }
}

// -------- logits = h2 @ Wo + bo. grid 256 = (m, n-chunk of 250) ------------
__global__ void __launch_bounds__(256) k_logits(const float* __restrict__ h2,
                                                const float* __restrict__ Wo,
                                                const float* __restrict__ bo,
                                                float* __restrict__ logits) {
  const int m = blockIdx.x >> 2;
  const int nc = blockIdx.x & 3;
  const int t = threadIdx.x;
  __shared__ float a[N2];
  a[t] = h2[(size_t)m * N2 + t];
  __syncthreads();
  const int col = nc * 250 + t;
  if (t >= 250) return;
  float sum = bo[col];
#pragma unroll 8
  for (int k = 0; k < N2; k++)
    sum = fmaf(a[k], Wo[(size_t)k * N3 + col], sum);
  logits[(size_t)m * N3 + col] = sum;
}

// -------- softmax over logits rows -> out ----------------------------------
__global__ void __launch_bounds__(256) k_softmax(const float* __restrict__ logits,
                                                 float* __restrict__ out) {
  const int m = blockIdx.x;
  const int t = threadIdx.x;
  __shared__ float red[8];
  float vals[4];
  float vmax = -3.4e38f;
#pragma unroll
  for (int j = 0; j < 4; j++) {
    int n = j * 256 + t;
    vals[j] = (n < N3) ? logits[(size_t)m * N3 + n] : -3.4e38f;
    vmax = fmaxf(vmax, vals[j]);
  }
#pragma unroll
  for (int off = 32; off > 0; off >>= 1) vmax = fmaxf(vmax, __shfl_xor(vmax, off));
  const int wid = t >> 6;
  if ((t & 63) == 0) red[wid] = vmax;
  __syncthreads();
  vmax = fmaxf(fmaxf(red[0], red[1]), fmaxf(red[2], red[3]));
  float ev[4];
  float esum = 0.f;
#pragma unroll
  for (int j = 0; j < 4; j++) {
    int n = j * 256 + t;
    float e = (n < N3) ? __expf(vals[j] - vmax) : 0.f;
    ev[j] = e;
    esum += e;
  }
#pragma unroll
  for (int off = 32; off > 0; off >>= 1) esum += __shfl_xor(esum, off);
  if ((t & 63) == 0) red[4 + wid] = esum;
  __syncthreads();
  esum = red[4] + red[5] + red[6] + red[7];
  float inv = 1.f / esum;
#pragma unroll
  for (int j = 0; j < 4; j++) {
    int n = j * 256 + t;
    if (n < N3) out[(size_t)m * N3 + n] = ev[j] * inv;
  }
}

extern "C" void kernel_launch(void* const* d_in, const int* in_sizes, int n_in,
                              void* d_out, int out_size, void* d_ws, size_t ws_size,
                              hipStream_t stream) {
  const float* x = (const float*)d_in[0];
  const float* filters = (const float*)d_in[1];
  const float* W1 = (const float*)d_in[2];
  const float* b1 = (const float*)d_in[3];
  const float* W2 = (const float*)d_in[4];
  const float* b2 = (const float*)d_in[5];
  const float* Wo = (const float*)d_in[6];
  const float* bo = (const float*)d_in[7];
  float* out = (float*)d_out;

  float* ws = (float*)d_ws;
  float* flat = ws;                                  // 64*98592 (padded)
  float* partial = flat + (size_t)Bsz * FEATP;       // 192*64*512
  float* partial2 = partial + (size_t)NCH * Bsz * N1;// 8*64*512
  float* h2 = partial2 + (size_t)RG * Bsz * N1;      // 64*256
  float* logits = h2 + (size_t)Bsz * N2;             // 64*1000

  k_convpool<<<(Bsz * PP + 255) / 256, 256, 0, stream>>>(x, filters, flat);
  k_gemm1<<<4 * NCH, 256, 0, stream>>>(flat, W1, partial);
  dim3 gr(Bsz * N1 / 4 / 256, RG);
  k_red1a<<<gr, 256, 0, stream>>>((const float4*)partial, (float4*)partial2);
  k_gemm2<<<Bsz * 4, 256, 0, stream>>>(partial2, b1, W2, b2, h2);
  k_logits<<<Bsz * 4, 256, 0, stream>>>(h2, Wo, bo, logits);
  k_softmax<<<Bsz, 256, 0, stream>>>(logits, out);
}